// Round 2
// baseline (170.731 us; speedup 1.0000x reference)
//
#include <hip/hip_runtime.h>
#include <math.h>

// ForceMatchingLoss — R5: R4 latency-hiding, hardened.
//  * sibling-XCD swizzle: b = bid&255, h = bid>>8 so both blocks of a batch
//    (which read the identical K stream twice: pass1 + staging) sit on the
//    SAME XCD L2 (default dispatch round-robins XCDs by blockIdx).
//  * 2-deep register prefetch (A/B sets) for pass2 staging, unroll-2 so
//    set selection is compile-time (no scratch), code size bounded.
//  * CG staging loads hoisted into the st==6 prefetch slot.
//  * ws scheme identical to proven R3: zero_ws + atomicAdd, 4KB footprint.
// agg_jac = SCALE * ( V^T diag(w) K - Out^T Kbar ), w_s = sum_q p_qs.
// Block h of pair handles V-dim rows [64h, 64h+64) of C and out; kbar full.

namespace {
constexpr int Bn = 256, Qn = 16, Sn = 512, Mn = 8, Dn = 128;
constexpr int NT = 512;
constexpr float SCALE = 0.08838834764831845f;  // 1/sqrt(128)
constexpr float CLIPV = 50.0f;

// LDS layout (bytes)
constexpr int QS    = 0;            // bf16 [16][136] stride 272  -> 4352
constexpr int PB    = 4352;         // bf16 [16][520] stride 1040 -> 16640
constexpr int WOFF  = 20992;        // f32 [512]                  -> 2048
constexpr int ARENA = 23040;        // 36864 (SCF aliases KT/VT/VTW)
constexpr int KT    = ARENA;        // bf16 [128][72] stride 144  -> 18432
constexpr int VT    = ARENA + 18432; // bf16 [64][72]             -> 9216
constexpr int VTW   = ARENA + 27648; // bf16 [64][72]             -> 9216
constexpr int SCF   = ARENA;        // f32 [16][516] stride 2064  -> 33024
constexpr int CGS   = 59904;        // f32 [16][8] stride 32      -> 512
constexpr int PCG   = 60416;        // bf16 [16][40] stride 80    -> 1280
constexpr int WC    = 61696;        // f32 [8]                    -> 32
constexpr int RED   = 61728;        // f32 [8][4]                 -> 128
constexpr int LDSZ  = 61856;        // < 64KB static; 2 blocks = 124KB < 160KB

typedef __attribute__((ext_vector_type(8))) short bf16x8;
typedef __attribute__((ext_vector_type(4))) float f32x4;
#define MFMA16(a, b, c) __builtin_amdgcn_mfma_f32_16x16x32_bf16((a), (b), (c), 0, 0, 0)

// truncating fp32->bf16 pair pack: 1 v_perm_b32
__device__ inline unsigned int pack2t(float a, float b) {
  return __builtin_amdgcn_perm(__builtin_bit_cast(unsigned int, b),
                               __builtin_bit_cast(unsigned int, a), 0x07060302u);
}
__device__ inline unsigned short f2bf(float x) {  // RNE (cold paths)
  unsigned int u = __builtin_bit_cast(unsigned int, x);
  u += 0x7fffu + ((u >> 16) & 1u);
  return (unsigned short)(u >> 16);
}
__device__ inline float bf2f(unsigned short h) {
  unsigned int u = ((unsigned int)h) << 16;
  return __builtin_bit_cast(float, u);
}
union Frag {
  bf16x8 v;
  unsigned int u[4];
  unsigned short h[8];
};

__global__ void zero_ws_kernel(float4* ws) {
  ws[threadIdx.x] = make_float4(0.f, 0.f, 0.f, 0.f);  // 256 thr * 4 = 1024 f32
}

__global__ void finalize_kernel(const float* __restrict__ ws, float* __restrict__ out) {
  __shared__ float sr[256];
  int i = threadIdx.x;
  float dt = ws[i * 4 + 0], n1 = ws[i * 4 + 1], n2 = ws[i * 4 + 2], cs = ws[i * 4 + 3];
  float cosv = dt / (sqrtf(n1) * sqrtf(n2) + 1e-8f);
  sr[i] = (1.0f - cosv) + cs * (1.0f / (float)(Qn * Dn));
  __syncthreads();
  for (int off = 128; off; off >>= 1) {
    if (i < off) sr[i] += sr[i + off];
    __syncthreads();
  }
  if (i == 0) out[0] = sr[0] * (1.0f / (float)Bn);
}

__global__ __launch_bounds__(NT, 4) void fm_kernel(
    const float* __restrict__ Qg, const float* __restrict__ Kg,
    const float* __restrict__ Vg, const float* __restrict__ Kcg,
    const float* __restrict__ Vcg, float* __restrict__ ws) {
  __shared__ __align__(16) char L[LDSZ];
  // Sibling-XCD co-location: blocks b and b+256 (same batch) are both
  // ≡ b (mod 8) -> same XCD -> shared L2 for the duplicated K stream.
  const int bid = blockIdx.x, b = bid & 255, h = bid >> 8;
  const int t = threadIdx.x, lane = t & 63, wv = t >> 6;
  const int quad = lane >> 4, l16 = lane & 15;

  const float* Qb = Qg + (size_t)b * Qn * Dn;
  const float* Kb = Kg + (size_t)b * Sn * Dn;
  const float* Vb = Vg + (size_t)b * Sn * Dn;
  const float* Kc = Kcg + (size_t)b * Mn * Dn;
  const float* Vc = Vcg + (size_t)b * Mn * Dn;

  // staging roles (pass 2): thread owns 8 consecutive s for one dim
  const int dK = t & 127, gK = t >> 7;  // K: octets gK, gK+4 of 8
  const int dV = t & 63, gV = t >> 6;   // V: octet gV (==wave, uniform)
  float kpfA[2][8], vpfA[8];            // prefetch set A (tiles 0,2,4,6)
  float kpfB[2][8], vpfB[8];            // prefetch set B (tiles 1,3,5,7)
  float cgkv[8];                        // hoisted CG staging values

  auto load_tiles = [&](int st, float (&kpf)[2][8], float (&vpf)[8]) {
#pragma unroll
    for (int o = 0; o < 2; ++o) {
      int s0 = st * 64 + (gK + 4 * o) * 8;
#pragma unroll
      for (int i = 0; i < 8; ++i) kpf[o][i] = Kb[(size_t)(s0 + i) * Dn + dK];
    }
    int s1 = st * 64 + gV * 8;
#pragma unroll
    for (int i = 0; i < 8; ++i) vpf[i] = Vb[(size_t)(s1 + i) * Dn + h * 64 + dV];
  };
  auto store_tiles = [&](int st, float (&kpf)[2][8], float (&vpf)[8]) {
#pragma unroll
    for (int o = 0; o < 2; ++o) {
      unsigned int u0 = pack2t(kpf[o][0], kpf[o][1]), u1 = pack2t(kpf[o][2], kpf[o][3]);
      unsigned int u2 = pack2t(kpf[o][4], kpf[o][5]), u3 = pack2t(kpf[o][6], kpf[o][7]);
      *(uint4*)(L + KT + dK * 144 + (gK + 4 * o) * 16) = make_uint4(u0, u1, u2, u3);
    }
    int s1 = st * 64 + gV * 8;
    float4 wlo = *(const float4*)(L + WOFF + s1 * 4);
    float4 whi = *(const float4*)(L + WOFF + s1 * 4 + 16);
    float wv8[8] = {wlo.x, wlo.y, wlo.z, wlo.w, whi.x, whi.y, whi.z, whi.w};
    unsigned int v0 = pack2t(vpf[0], vpf[1]), v1 = pack2t(vpf[2], vpf[3]);
    unsigned int v2 = pack2t(vpf[4], vpf[5]), v3 = pack2t(vpf[6], vpf[7]);
    *(uint4*)(L + VT + dV * 144 + gV * 16) = make_uint4(v0, v1, v2, v3);
    unsigned int w0 = pack2t(wv8[0] * vpf[0], wv8[1] * vpf[1]);
    unsigned int w1 = pack2t(wv8[2] * vpf[2], wv8[3] * vpf[3]);
    unsigned int w2 = pack2t(wv8[4] * vpf[4], wv8[5] * vpf[5]);
    unsigned int w3 = pack2t(wv8[6] * vpf[6], wv8[7] * vpf[7]);
    *(uint4*)(L + VTW + dV * 144 + gV * 16) = make_uint4(w0, w1, w2, w3);
  };

  // ---- Q (pre-scaled) -> QS bf16 ----
  {
    int row = t >> 5, c4 = t & 31;
    float4 qv = ((const float4*)Qb)[t];
    unsigned int p0 = pack2t(qv.x * SCALE, qv.y * SCALE);
    unsigned int p1 = pack2t(qv.z * SCALE, qv.w * SCALE);
    *(unsigned long long*)(L + QS + row * 272 + c4 * 8) =
        (unsigned long long)p0 | ((unsigned long long)p1 << 32);
  }
  load_tiles(0, kpfA, vpfA);  // deep prefetch for pass2 tile 0
  __syncthreads();

  // ---- Pass 1: scores, each wave an independent 16x64 strip (no barriers) ----
  {
    bf16x8 aq[4];
#pragma unroll
    for (int kk = 0; kk < 4; ++kk)
      aq[kk] = *(const bf16x8*)(L + QS + l16 * 272 + kk * 64 + quad * 16);
    for (int j = 0; j < 4; ++j) {
      int srow = 64 * wv + 16 * j + l16;
      const float* kp = Kb + (size_t)srow * Dn + quad * 8;
      f32x4 acc = {0.f, 0.f, 0.f, 0.f};
#pragma unroll
      for (int kk = 0; kk < 4; ++kk) {
        float4 lo = *(const float4*)(kp + kk * 32);
        float4 hi = *(const float4*)(kp + kk * 32 + 4);
        Frag f;
        f.u[0] = pack2t(lo.x, lo.y);
        f.u[1] = pack2t(lo.z, lo.w);
        f.u[2] = pack2t(hi.x, hi.y);
        f.u[3] = pack2t(hi.z, hi.w);
        acc = MFMA16(aq[kk], f.v, acc);
      }
      int s = 64 * wv + 16 * j + l16;
#pragma unroll
      for (int r = 0; r < 4; ++r)
        *(float*)(L + SCF + (quad * 4 + r) * 2064 + s * 4) = acc[r];
    }
  }
  load_tiles(1, kpfB, vpfB);  // 2nd-deep prefetch: covered by softmax + tile0
  __syncthreads();

  // ---- Softmax: wave wv owns rows 2wv, 2wv+1; write bf16 probs -> PB ----
#pragma unroll
  for (int rr = 0; rr < 2; ++rr) {
    int q = wv * 2 + rr;
    const float* srow = (const float*)(L + SCF + q * 2064);
    float x[8];
    float m = -1e30f;
#pragma unroll
    for (int i = 0; i < 8; ++i) { x[i] = srow[lane * 8 + i]; m = fmaxf(m, x[i]); }
#pragma unroll
    for (int o = 32; o; o >>= 1) m = fmaxf(m, __shfl_xor(m, o));
    float ssum = 0.f;
#pragma unroll
    for (int i = 0; i < 8; ++i) { x[i] = __expf(x[i] - m); ssum += x[i]; }
#pragma unroll
    for (int o = 32; o; o >>= 1) ssum += __shfl_xor(ssum, o);
    float inv = 1.f / ssum;
    Frag g;
#pragma unroll
    for (int i = 0; i < 8; ++i) g.h[i] = f2bf(x[i] * inv);
    *(bf16x8*)(L + PB + q * 1040 + lane * 16) = g.v;
  }
  __syncthreads();
  {  // w_s = sum_q p_qs
    float wsv = 0.f;
#pragma unroll
    for (int q = 0; q < Qn; ++q)
      wsv += bf2f(*(const unsigned short*)(L + PB + q * 1040 + t * 2));
    *(float*)(L + WOFF + t * 4) = wsv;
  }
  __syncthreads();

  // ---- Pass 2: 8 iterations of 64 s-rows, 2-deep prefetch ----
  const int rp = wv & 1, ch = wv >> 1;  // C tile: rows rp*32, cols ch*32 (local)
  f32x4 C00 = {0.f,0.f,0.f,0.f}, C01 = {0.f,0.f,0.f,0.f};
  f32x4 C10 = {0.f,0.f,0.f,0.f}, C11 = {0.f,0.f,0.f,0.f};
  f32x4 outacc = {0.f,0.f,0.f,0.f}, kbacc = {0.f,0.f,0.f,0.f};

  auto ckstep = [&](int colByte, f32x4& c00, f32x4& c01, f32x4& c10, f32x4& c11) {
    bf16x8 A0 = *(const bf16x8*)(L + VTW + (rp * 32 + l16) * 144 + colByte + quad * 16);
    bf16x8 A1 = *(const bf16x8*)(L + VTW + (rp * 32 + 16 + l16) * 144 + colByte + quad * 16);
    bf16x8 B0 = *(const bf16x8*)(L + KT + (ch * 32 + l16) * 144 + colByte + quad * 16);
    bf16x8 B1 = *(const bf16x8*)(L + KT + (ch * 32 + 16 + l16) * 144 + colByte + quad * 16);
    c00 = MFMA16(A0, B0, c00);
    c01 = MFMA16(A0, B1, c01);
    c10 = MFMA16(A1, B0, c10);
    c11 = MFMA16(A1, B1, c11);
  };

#pragma unroll 2
  for (int st = 0; st < 8; ++st) {
    if (st) __syncthreads();
    if (st & 1) store_tiles(st, kpfB, vpfB);
    else       store_tiles(st, kpfA, vpfA);
    __syncthreads();
    if (st < 6) {  // refill the set just consumed: issue->use gap = 2 tiles
      if (st & 1) load_tiles(st + 2, kpfB, vpfB);
      else        load_tiles(st + 2, kpfA, vpfA);
    } else if (st == 6) {  // hoist CG staging loads behind remaining compute
      if (t < 128) {
#pragma unroll
        for (int i = 0; i < 8; ++i) cgkv[i] = Kc[(size_t)i * Dn + t];
      } else if (t < 256) {
        int d = (t - 128) & 63;
#pragma unroll
        for (int i = 0; i < 8; ++i) cgkv[i] = Vc[(size_t)i * Dn + h * 64 + d];
      }
    }
#pragma unroll
    for (int z = 0; z < 2; ++z) {
      int colByte = z * 64;
      bf16x8 pA = *(const bf16x8*)(L + PB + l16 * 1040 + st * 128 + z * 64 + quad * 16);
      bf16x8 bK = *(const bf16x8*)(L + KT + (wv * 16 + l16) * 144 + colByte + quad * 16);
      kbacc = MFMA16(pA, bK, kbacc);
      if (wv < 4) {
        bf16x8 bV = *(const bf16x8*)(L + VT + (wv * 16 + l16) * 144 + colByte + quad * 16);
        outacc = MFMA16(pA, bV, outacc);
      }
      ckstep(colByte, C00, C01, C10, C11);
    }
  }
  __syncthreads();

  // ---- Dense pseudo k-step: C -= Out^T · Kbar ----
  if (wv < 4) {
#pragma unroll
    for (int r = 0; r < 4; ++r)
      *(unsigned short*)(L + VTW + (wv * 16 + l16) * 144 + (quad * 4 + r) * 2) = f2bf(-outacc[r]);
  }
#pragma unroll
  for (int r = 0; r < 4; ++r)
    *(unsigned short*)(L + KT + (wv * 16 + l16) * 144 + (quad * 4 + r) * 2) = f2bf(kbacc[r]);
  if (t < 256) {
    *(uint4*)(L + KT + (t >> 1) * 144 + 32 + (t & 1) * 16) = make_uint4(0, 0, 0, 0);
  } else if (t < 384) {
    int i = t - 256;
    *(uint4*)(L + VTW + (i >> 1) * 144 + 32 + (i & 1) * 16) = make_uint4(0, 0, 0, 0);
  }
  __syncthreads();
  ckstep(0, C00, C01, C10, C11);
#pragma unroll
  for (int r = 0; r < 4; ++r) {
    C00[r] = fminf(fmaxf(SCALE * C00[r], -CLIPV), CLIPV);
    C01[r] = fminf(fmaxf(SCALE * C01[r], -CLIPV), CLIPV);
    C10[r] = fminf(fmaxf(SCALE * C10[r], -CLIPV), CLIPV);
    C11[r] = fminf(fmaxf(SCALE * C11[r], -CLIPV), CLIPV);
  }
  __syncthreads();  // arena free for CG

  // ---- CG scores (wave 0, direct from global) ----
  if (wv == 0) {
    f32x4 acc = {0.f, 0.f, 0.f, 0.f};
    const float* kp = Kc + (size_t)(l16 & 7) * Dn + quad * 8;
#pragma unroll
    for (int kk = 0; kk < 4; ++kk) {
      bf16x8 a = *(const bf16x8*)(L + QS + l16 * 272 + kk * 64 + quad * 16);
      float4 lo = *(const float4*)(kp + kk * 32);
      float4 hi = *(const float4*)(kp + kk * 32 + 4);
      Frag f;
      f.u[0] = pack2t(lo.x, lo.y);
      f.u[1] = pack2t(lo.z, lo.w);
      f.u[2] = pack2t(hi.x, hi.y);
      f.u[3] = pack2t(hi.z, hi.w);
      acc = MFMA16(a, f.v, acc);
    }
    if (l16 < 8) {
#pragma unroll
      for (int r = 0; r < 4; ++r)
        *(float*)(L + CGS + (quad * 4 + r) * 32 + l16 * 4) = acc[r];
    }
  }
  __syncthreads();
  if (t < 16) {  // cg softmax row t -> PCG (cols 8..31 zeroed)
    float xs[8];
    float m = -1e30f;
#pragma unroll
    for (int s = 0; s < 8; ++s) { xs[s] = *(const float*)(L + CGS + t * 32 + s * 4); m = fmaxf(m, xs[s]); }
    float ssum = 0.f;
#pragma unroll
    for (int s = 0; s < 8; ++s) { xs[s] = __expf(xs[s] - m); ssum += xs[s]; }
    float inv = 1.f / ssum;
#pragma unroll
    for (int s = 0; s < 4; ++s)
      *(unsigned int*)(L + PCG + t * 80 + s * 4) = pack2t(xs[2 * s] * inv, xs[2 * s + 1] * inv);
#pragma unroll
    for (int p = 4; p < 16; ++p) *(unsigned int*)(L + PCG + t * 80 + p * 4) = 0u;
  }
  __syncthreads();
  if (t < 8) {
    float s = 0.f;
#pragma unroll
    for (int q = 0; q < Qn; ++q) s += bf2f(*(const unsigned short*)(L + PCG + q * 80 + t * 2));
    *(float*)(L + WC + t * 4) = s;
  }
  __syncthreads();
  // ---- stage CG transposed (cols 8..31 zero) — from hoisted registers ----
  if (t < 128) {
    *(uint4*)(L + KT + t * 144) = make_uint4(pack2t(cgkv[0], cgkv[1]), pack2t(cgkv[2], cgkv[3]),
                                             pack2t(cgkv[4], cgkv[5]), pack2t(cgkv[6], cgkv[7]));
    *(uint4*)(L + KT + t * 144 + 16) = make_uint4(0, 0, 0, 0);
    *(uint4*)(L + KT + t * 144 + 32) = make_uint4(0, 0, 0, 0);
    *(uint4*)(L + KT + t * 144 + 48) = make_uint4(0, 0, 0, 0);
  } else if (t < 192) {
    int d = t - 128;
    *(uint4*)(L + VT + d * 144) = make_uint4(pack2t(cgkv[0], cgkv[1]), pack2t(cgkv[2], cgkv[3]),
                                             pack2t(cgkv[4], cgkv[5]), pack2t(cgkv[6], cgkv[7]));
    *(uint4*)(L + VT + d * 144 + 16) = make_uint4(0, 0, 0, 0);
    *(uint4*)(L + VT + d * 144 + 32) = make_uint4(0, 0, 0, 0);
    *(uint4*)(L + VT + d * 144 + 48) = make_uint4(0, 0, 0, 0);
  } else if (t < 256) {
    int d = t - 192;
    float wcv[8];
#pragma unroll
    for (int i = 0; i < 8; ++i) wcv[i] = *(const float*)(L + WC + i * 4);
    *(uint4*)(L + VTW + d * 144) =
        make_uint4(pack2t(wcv[0] * cgkv[0], wcv[1] * cgkv[1]), pack2t(wcv[2] * cgkv[2], wcv[3] * cgkv[3]),
                   pack2t(wcv[4] * cgkv[4], wcv[5] * cgkv[5]), pack2t(wcv[6] * cgkv[6], wcv[7] * cgkv[7]));
    *(uint4*)(L + VTW + d * 144 + 16) = make_uint4(0, 0, 0, 0);
    *(uint4*)(L + VTW + d * 144 + 32) = make_uint4(0, 0, 0, 0);
    *(uint4*)(L + VTW + d * 144 + 48) = make_uint4(0, 0, 0, 0);
  }
  __syncthreads();
  f32x4 outc = {0.f,0.f,0.f,0.f}, kbc = {0.f,0.f,0.f,0.f};
  f32x4 D00 = {0.f,0.f,0.f,0.f}, D01 = {0.f,0.f,0.f,0.f};
  f32x4 D10 = {0.f,0.f,0.f,0.f}, D11 = {0.f,0.f,0.f,0.f};
  {
    bf16x8 pA = *(const bf16x8*)(L + PCG + l16 * 80 + quad * 16);
    bf16x8 bK = *(const bf16x8*)(L + KT + (wv * 16 + l16) * 144 + quad * 16);
    kbc = MFMA16(pA, bK, kbc);
    if (wv < 4) {
      bf16x8 bV = *(const bf16x8*)(L + VT + (wv * 16 + l16) * 144 + quad * 16);
      outc = MFMA16(pA, bV, outc);
    }
    ckstep(0, D00, D01, D10, D11);
  }
  __syncthreads();
  // cg pseudo k-step (bytes 32..63 of rows are already zero from staging)
  if (wv < 4) {
#pragma unroll
    for (int r = 0; r < 4; ++r)
      *(unsigned short*)(L + VTW + (wv * 16 + l16) * 144 + (quad * 4 + r) * 2) = f2bf(-outc[r]);
  }
#pragma unroll
  for (int r = 0; r < 4; ++r)
    *(unsigned short*)(L + KT + (wv * 16 + l16) * 144 + (quad * 4 + r) * 2) = f2bf(kbc[r]);
  __syncthreads();
  ckstep(0, D00, D01, D10, D11);
#pragma unroll
  for (int r = 0; r < 4; ++r) {
    D00[r] = fminf(fmaxf(SCALE * D00[r], -CLIPV), CLIPV);
    D01[r] = fminf(fmaxf(SCALE * D01[r], -CLIPV), CLIPV);
    D10[r] = fminf(fmaxf(SCALE * D10[r], -CLIPV), CLIPV);
    D11[r] = fminf(fmaxf(SCALE * D11[r], -CLIPV), CLIPV);
  }

  // ---- Loss partials ----
  float dot = 0.f, nd2 = 0.f, nc2 = 0.f, cons = 0.f;
#pragma unroll
  for (int r = 0; r < 4; ++r) {
    dot += C00[r] * D00[r] + C01[r] * D01[r] + C10[r] * D10[r] + C11[r] * D11[r];
    nd2 += C00[r] * C00[r] + C01[r] * C01[r] + C10[r] * C10[r] + C11[r] * C11[r];
    nc2 += D00[r] * D00[r] + D01[r] * D01[r] + D10[r] * D10[r] + D11[r] * D11[r];
  }
  if (wv < 4) {
#pragma unroll
    for (int r = 0; r < 4; ++r) {
      float df = outacc[r] - outc[r];
      cons += df * df;
    }
  }
#pragma unroll
  for (int o = 32; o; o >>= 1) {
    dot += __shfl_xor(dot, o);
    nd2 += __shfl_xor(nd2, o);
    nc2 += __shfl_xor(nc2, o);
    cons += __shfl_xor(cons, o);
  }
  if (lane == 0) {
    float* red = (float*)(L + RED);
    red[wv * 4 + 0] = dot;
    red[wv * 4 + 1] = nd2;
    red[wv * 4 + 2] = nc2;
    red[wv * 4 + 3] = cons;
  }
  __syncthreads();
  if (t == 0) {
    const float* red = (const float*)(L + RED);
    float d_ = 0.f, n1 = 0.f, n2 = 0.f, cs = 0.f;
#pragma unroll
    for (int w = 0; w < 8; ++w) {
      d_ += red[w * 4 + 0];
      n1 += red[w * 4 + 1];
      n2 += red[w * 4 + 2];
      cs += red[w * 4 + 3];
    }
    atomicAdd(ws + b * 4 + 0, d_);
    atomicAdd(ws + b * 4 + 1, n1);
    atomicAdd(ws + b * 4 + 2, n2);
    atomicAdd(ws + b * 4 + 3, cs);
  }
}
}  // namespace

extern "C" void kernel_launch(void* const* d_in, const int* in_sizes, int n_in,
                              void* d_out, int out_size, void* d_ws, size_t ws_size,
                              hipStream_t stream) {
  const float* q = (const float*)d_in[0];
  const float* k = (const float*)d_in[1];
  const float* v = (const float*)d_in[2];
  const float* kc = (const float*)d_in[3];
  const float* vc = (const float*)d_in[4];
  float* out = (float*)d_out;
  float* ws = (float*)d_ws;
  zero_ws_kernel<<<1, 256, 0, stream>>>((float4*)ws);
  fm_kernel<<<2 * Bn, NT, 0, stream>>>(q, k, v, kc, vc, ws);
  finalize_kernel<<<1, 256, 0, stream>>>(ws, out);
}